// Round 1
// baseline (3287.107 us; speedup 1.0000x reference)
//
#include <hip/hip_runtime.h>

static constexpr int GRAPHS = 256;

__device__ __forceinline__ float lrelu(float v) { return fmaxf(v, 0.2f * v); }

// ---------------- utility ----------------
__global__ void zero_f32_kernel(float* __restrict__ p, int n) {
  int i = blockIdx.x * blockDim.x + threadIdx.x;
  if (i < n) p[i] = 0.0f;
}

// ---------------- CSR build (target-major adjacency incl. self loops) ----------------
__global__ void init_counts_kernel(int* __restrict__ cnt, int n) {
  int i = blockIdx.x * blockDim.x + threadIdx.x;
  if (i < n) cnt[i] = 1;  // self loop
}

__global__ void count_edges_kernel(const int* __restrict__ ei, int* __restrict__ cnt, int E) {
  int e = blockIdx.x * blockDim.x + threadIdx.x;
  if (e < E) atomicAdd(&cnt[ei[E + e]], 1);  // col = target
}

__global__ void scan_kernel(const int* __restrict__ counts, int* __restrict__ rowptr, int n) {
  __shared__ int sh[1024];
  int t = threadIdx.x;
  int chunk = (n + 1023) >> 10;
  int start = t * chunk;
  int end = min(start + chunk, n);
  int sum = 0;
  for (int i = start; i < end; ++i) sum += counts[i];
  sh[t] = sum;
  __syncthreads();
  for (int off = 1; off < 1024; off <<= 1) {
    int v = (t >= off) ? sh[t - off] : 0;
    __syncthreads();
    sh[t] += v;
    __syncthreads();
  }
  int run = sh[t] - sum;  // exclusive prefix
  for (int i = start; i < end; ++i) { rowptr[i] = run; run += counts[i]; }
  if (t == 1023) rowptr[n] = sh[1023];
}

__global__ void finalize_csr_kernel(const int* __restrict__ rowptr, float* __restrict__ dis,
                                    int* __restrict__ cursor, int* __restrict__ csr, int n) {
  int i = blockIdx.x * blockDim.x + threadIdx.x;
  if (i >= n) return;
  int s = rowptr[i], e = rowptr[i + 1];
  dis[i] = rsqrtf((float)(e - s));  // deg includes self loop, >= 1
  csr[s] = i;                       // self loop in slot 0
  cursor[i] = s + 1;
}

__global__ void fill_edges_kernel(const int* __restrict__ ei, int* __restrict__ cursor,
                                  int* __restrict__ csr, int E) {
  int e = blockIdx.x * blockDim.x + threadIdx.x;
  if (e >= E) return;
  int c = ei[E + e];                     // target
  int pos = atomicAdd(&cursor[c], 1);
  csr[pos] = ei[e];                      // source
}

// ---------------- dense GEMM: out[n,c] = sum_k x[n,k] * W[k,c] ----------------
template <int DIN, int DOUT>
__global__ void gemm_kernel(const float* __restrict__ x, const float* __restrict__ W,
                            float* __restrict__ out, int n_nodes) {
  int gid = blockIdx.x * blockDim.x + threadIdx.x;
  if (gid >= n_nodes * DOUT) return;
  int n = gid / DOUT;
  int c = gid & (DOUT - 1);
  const float* xr = x + (size_t)n * DIN;
  float acc = 0.f;
#pragma unroll 16
  for (int k = 0; k < DIN; ++k) acc = fmaf(xr[k], W[k * DOUT + c], acc);
  out[gid] = acc;
}

// ---------------- GCN aggregation: wave per node, atomic-free ----------------
template <int D>
__global__ void gcn_agg_kernel(const float* __restrict__ h, const int* __restrict__ rowptr,
                               const int* __restrict__ csr, const float* __restrict__ dis,
                               const float* __restrict__ bias, float* __restrict__ out, int n) {
  int wave = (blockIdx.x * blockDim.x + threadIdx.x) >> 6;
  int lane = threadIdx.x & 63;
  if (wave >= n) return;
  int s = rowptr[wave], e = rowptr[wave + 1];
  float acc0 = 0.f, acc1 = 0.f;
  for (int k = s; k < e; ++k) {
    int j = csr[k];
    float dj = dis[j];
    const float* hr = h + (size_t)j * D;
    acc0 = fmaf(dj, hr[lane], acc0);
    if (D == 128) acc1 = fmaf(dj, hr[lane + 64], acc1);
  }
  float di = dis[wave];
  out[(size_t)wave * D + lane] = fmaf(di, acc0, bias[lane]);
  if (D == 128) out[(size_t)wave * D + lane + 64] = fmaf(di, acc1, bias[lane + 64]);
}

// ---------------- BatchNorm ----------------
template <int D>
__global__ void bn_stats_kernel(const float* __restrict__ x, double* __restrict__ stats, int n) {
  int tid = threadIdx.x;
  int c = tid & (D - 1);
  const int rpb = 256 / D;
  float s1 = 0.f, s2 = 0.f;
  for (int r = blockIdx.x * rpb + tid / D; r < n; r += gridDim.x * rpb) {
    float v = x[(size_t)r * D + c];
    s1 += v;
    s2 = fmaf(v, v, s2);
  }
  atomicAdd(&stats[c], (double)s1);
  atomicAdd(&stats[D + c], (double)s2);
}

template <int D>
__global__ void bn_coef_kernel(const double* __restrict__ stats, const float* __restrict__ g,
                               const float* __restrict__ b, float* __restrict__ coef, int n) {
  int c = threadIdx.x;
  if (c >= D) return;
  double inv_n = 1.0 / (double)n;
  double mu = stats[c] * inv_n;
  double var = stats[D + c] * inv_n - mu * mu;  // biased variance (jnp.var)
  float A = (float)(1.0 / sqrt(var + 1e-5)) * g[c];
  coef[c] = A;
  coef[D + c] = b[c] - (float)mu * A;
}

template <int D, bool ACT>
__global__ void bn_apply_kernel(float* __restrict__ x, const float* __restrict__ coef, int total) {
  int gid = blockIdx.x * blockDim.x + threadIdx.x;
  if (gid >= total) return;
  int c = gid & (D - 1);
  float v = fmaf(x[gid], coef[c], coef[D + c]);
  if (ACT) v = lrelu(v);
  x[gid] = v;
}

// ---------------- GAT ----------------
// per-node per-head attention coefficients: asrc[n,h] = <h2[n,h,:], a_src[h,:]>
template <int C>
__global__ void att_coef_kernel(const float* __restrict__ h2, const float* __restrict__ a_src,
                                const float* __restrict__ a_dst, float* __restrict__ asrc,
                                float* __restrict__ adst, int n) {
  int gid = blockIdx.x * blockDim.x + threadIdx.x;
  if (gid >= n * 4) return;
  int nd = gid >> 2, h = gid & 3;
  const float* hr = h2 + (size_t)nd * 4 * C + h * C;
  float s1 = 0.f, s2 = 0.f;
#pragma unroll
  for (int c = 0; c < C; ++c) {
    float v = hr[c];
    s1 = fmaf(v, a_src[h * C + c], s1);
    s2 = fmaf(v, a_dst[h * C + c], s2);
  }
  asrc[gid] = s1;
  adst[gid] = s2;
}

// wave per node; softmax over incoming edges is local (shift-invariant, no max pass).
// out = lrelu( sum_j exp(e_j) h2[j] / sum_j exp(e_j) + bias + xres )
template <int D, int C>
__global__ void gat_agg_kernel(const float* __restrict__ h2, const int* __restrict__ rowptr,
                               const int* __restrict__ csr, const float* __restrict__ asrc,
                               const float* __restrict__ adst, const float* __restrict__ bias,
                               const float* __restrict__ xres, float* __restrict__ out, int n) {
  int wave = (blockIdx.x * blockDim.x + threadIdx.x) >> 6;
  int lane = threadIdx.x & 63;
  if (wave >= n) return;
  const int h0 = lane / C;
  float ad0 = adst[wave * 4 + h0];
  float ad1 = 0.f;
  int h1 = 0;
  if (D == 128) {
    h1 = (lane + 64) / C;
    ad1 = adst[wave * 4 + h1];
  }
  float acc0 = 0.f, ss0 = 0.f, acc1 = 0.f, ss1 = 0.f;
  int s = rowptr[wave], e = rowptr[wave + 1];
  for (int k = s; k < e; ++k) {
    int j = csr[k];
    const float* hr = h2 + (size_t)j * D;
    float e0 = lrelu(asrc[j * 4 + h0] + ad0);
    float ex0 = __expf(e0);
    ss0 += ex0;
    acc0 = fmaf(ex0, hr[lane], acc0);
    if (D == 128) {
      float e1 = lrelu(asrc[j * 4 + h1] + ad1);
      float ex1 = __expf(e1);
      ss1 += ex1;
      acc1 = fmaf(ex1, hr[lane + 64], acc1);
    }
  }
  size_t base = (size_t)wave * D;
  float v0 = acc0 / ss0 + bias[lane] + xres[base + lane];
  out[base + lane] = lrelu(v0);
  if (D == 128) {
    float v1 = acc1 / ss1 + bias[lane + 64] + xres[base + lane + 64];
    out[base + lane + 64] = lrelu(v1);
  }
}

// ---------------- global mean pool ----------------
__global__ void pool_sum_kernel(const float* __restrict__ x, const int* __restrict__ batch,
                                float* __restrict__ pool, float* __restrict__ cnt, int n) {
  int gid = blockIdx.x * blockDim.x + threadIdx.x;
  if (gid >= n * 64) return;
  int nd = gid >> 6, c = gid & 63;
  int g = batch[nd];
  atomicAdd(&pool[(g << 6) + c], x[gid]);
  if (c == 0) atomicAdd(&cnt[g], 1.0f);
}

__global__ void pool_div_kernel(float* __restrict__ out, const float* __restrict__ pool,
                                const float* __restrict__ cnt) {
  int gid = blockIdx.x * blockDim.x + threadIdx.x;
  if (gid >= GRAPHS * 64) return;
  out[gid] = pool[gid] / fmaxf(cnt[gid >> 6], 1.0f);
}

// ---------------- host ----------------
extern "C" void kernel_launch(void* const* d_in, const int* in_sizes, int n_in, void* d_out,
                              int out_size, void* d_ws, size_t ws_size, hipStream_t stream) {
  const float* x_in = (const float*)d_in[0];
  const int* ei = (const int*)d_in[1];
  const int* batch = (const int*)d_in[2];
  const float* gcn_w[4] = {(const float*)d_in[3], (const float*)d_in[7], (const float*)d_in[11],
                           (const float*)d_in[15]};
  const float* gcn_b[4] = {(const float*)d_in[4], (const float*)d_in[8], (const float*)d_in[12],
                           (const float*)d_in[16]};
  const float* bn_g[4] = {(const float*)d_in[5], (const float*)d_in[9], (const float*)d_in[13],
                          (const float*)d_in[17]};
  const float* bn_b[4] = {(const float*)d_in[6], (const float*)d_in[10], (const float*)d_in[14],
                          (const float*)d_in[18]};
  const float* gat_w0 = (const float*)d_in[19];
  const float* gat_as0 = (const float*)d_in[20];
  const float* gat_ad0 = (const float*)d_in[21];
  const float* gat_b0 = (const float*)d_in[22];
  const float* gat_w2 = (const float*)d_in[23];
  const float* gat_as2 = (const float*)d_in[24];
  const float* gat_ad2 = (const float*)d_in[25];
  const float* gat_b2 = (const float*)d_in[26];

  const int N = in_sizes[2];      // 100000
  const int E = in_sizes[1] / 2;  // 1600000

  // workspace carve, 256B-aligned slices
  char* wp = (char*)d_ws;
  auto alloc = [&](size_t bytes) -> void* {
    void* p = (void*)wp;
    wp += (bytes + 255) & ~(size_t)255;
    return p;
  };
  double* stats = (double*)alloc(256 * sizeof(double));
  float* coef = (float*)alloc(256 * sizeof(float));
  int* rowptr = (int*)alloc((size_t)(N + 1) * 4);
  int* cursor = (int*)alloc((size_t)N * 4);
  int* csr = (int*)alloc((size_t)(N + E) * 4);
  float* dis = (float*)alloc((size_t)N * 4);
  float* bufA = (float*)alloc((size_t)N * 128 * 4);
  float* bufB = (float*)alloc((size_t)N * 128 * 4);
  float* bufC = (float*)alloc((size_t)N * 128 * 4);
  float* attS = (float*)alloc((size_t)N * 4 * 4);
  float* attD = (float*)alloc((size_t)N * 4 * 4);
  float* pool = (float*)alloc((size_t)GRAPHS * 64 * 4);
  float* cnt = (float*)alloc((size_t)GRAPHS * 4);
  if ((size_t)(wp - (char*)d_ws) > ws_size) return;  // insufficient workspace -> visible failure

  const int B = 256;
  auto cd = [](int a, int b) { return (a + b - 1) / b; };

  // --- CSR build ---
  init_counts_kernel<<<cd(N, B), B, 0, stream>>>(cursor, N);
  count_edges_kernel<<<cd(E, B), B, 0, stream>>>(ei, cursor, E);
  scan_kernel<<<1, 1024, 0, stream>>>(cursor, rowptr, N);
  finalize_csr_kernel<<<cd(N, B), B, 0, stream>>>(rowptr, dis, cursor, csr, N);
  fill_edges_kernel<<<cd(E, B), B, 0, stream>>>(ei, cursor, csr, E);

  auto bn = [&](float* buf, int D, const float* g, const float* b, bool act) {
    zero_f32_kernel<<<cd(512, B), B, 0, stream>>>((float*)stats, 512);
    if (D == 64) {
      bn_stats_kernel<64><<<256, 256, 0, stream>>>(buf, stats, N);
      bn_coef_kernel<64><<<1, 64, 0, stream>>>(stats, g, b, coef, N);
      int total = N * 64;
      if (act)
        bn_apply_kernel<64, true><<<cd(total, B), B, 0, stream>>>(buf, coef, total);
      else
        bn_apply_kernel<64, false><<<cd(total, B), B, 0, stream>>>(buf, coef, total);
    } else {
      bn_stats_kernel<128><<<256, 256, 0, stream>>>(buf, stats, N);
      bn_coef_kernel<128><<<1, 128, 0, stream>>>(stats, g, b, coef, N);
      int total = N * 128;
      if (act)
        bn_apply_kernel<128, true><<<cd(total, B), B, 0, stream>>>(buf, coef, total);
      else
        bn_apply_kernel<128, false><<<cd(total, B), B, 0, stream>>>(buf, coef, total);
    }
  };

  // ---- Layer 0: GCN 16->64, BN ----
  gemm_kernel<16, 64><<<cd(N * 64, B), B, 0, stream>>>(x_in, gcn_w[0], bufB, N);
  gcn_agg_kernel<64><<<cd(N * 64, B), B, 0, stream>>>(bufB, rowptr, csr, dis, gcn_b[0], bufC, N);
  bn(bufC, 64, bn_g[0], bn_b[0], false);
  // GAT0 (D=64, C=16) + residual + lrelu -> bufA
  gemm_kernel<64, 64><<<cd(N * 64, B), B, 0, stream>>>(bufC, gat_w0, bufB, N);
  att_coef_kernel<16><<<cd(N * 4, B), B, 0, stream>>>(bufB, gat_as0, gat_ad0, attS, attD, N);
  gat_agg_kernel<64, 16><<<cd(N * 64, B), B, 0, stream>>>(bufB, rowptr, csr, attS, attD, gat_b0,
                                                          bufC, bufA, N);

  // ---- Layer 1: GCN 64->128, BN + lrelu -> bufC ----
  gemm_kernel<64, 128><<<cd(N * 128, B), B, 0, stream>>>(bufA, gcn_w[1], bufB, N);
  gcn_agg_kernel<128><<<cd(N * 64, B), B, 0, stream>>>(bufB, rowptr, csr, dis, gcn_b[1], bufC, N);
  bn(bufC, 128, bn_g[1], bn_b[1], true);

  // ---- Layer 2: GCN 128->128, BN ----
  gemm_kernel<128, 128><<<cd(N * 128, B), B, 0, stream>>>(bufC, gcn_w[2], bufB, N);
  gcn_agg_kernel<128><<<cd(N * 64, B), B, 0, stream>>>(bufB, rowptr, csr, dis, gcn_b[2], bufA, N);
  bn(bufA, 128, bn_g[2], bn_b[2], false);
  // GAT2 (D=128, C=32) + residual + lrelu -> bufC
  gemm_kernel<128, 128><<<cd(N * 128, B), B, 0, stream>>>(bufA, gat_w2, bufB, N);
  att_coef_kernel<32><<<cd(N * 4, B), B, 0, stream>>>(bufB, gat_as2, gat_ad2, attS, attD, N);
  gat_agg_kernel<128, 32><<<cd(N * 64, B), B, 0, stream>>>(bufB, rowptr, csr, attS, attD, gat_b2,
                                                           bufA, bufC, N);

  // ---- Layer 3: GCN 128->64, BN (no act) -> bufA ----
  gemm_kernel<128, 64><<<cd(N * 64, B), B, 0, stream>>>(bufC, gcn_w[3], bufB, N);
  gcn_agg_kernel<64><<<cd(N * 64, B), B, 0, stream>>>(bufB, rowptr, csr, dis, gcn_b[3], bufA, N);
  bn(bufA, 64, bn_g[3], bn_b[3], false);

  // ---- global mean pool ----
  zero_f32_kernel<<<cd(GRAPHS * 64, B), B, 0, stream>>>(pool, GRAPHS * 64);
  zero_f32_kernel<<<1, 256, 0, stream>>>(cnt, GRAPHS);
  pool_sum_kernel<<<cd(N * 64, B), B, 0, stream>>>(bufA, batch, pool, cnt, N);
  pool_div_kernel<<<cd(GRAPHS * 64, B), B, 0, stream>>>((float*)d_out, pool, cnt);
}